// Round 11
// baseline (1219.335 us; speedup 1.0000x reference)
//
#include <hip/hip_runtime.h>

// HMM forward, B=64, T=1024, S=512, V=1024.
// Round 11: K-CHUNK OWNERSHIP. Each wave quantizes its own 64 states against
// its WAVE-LOCAL max (DPP, no barrier), packs the 64 u8 into an A-fragment
// IN-REGISTER (2 quad-perm DPP + shifts, then 4 ds_swizzle quad-gathers), and
// runs 32 independent mfma_i32_16x16x64_i8 (its K=64 chunk x all 512 cols;
// Bg[tau] = EqB4[(tau*8+wv)*64+lane], same EqB layout). Partial dots written
// to LDS part[pb][wv][col] (lanes 0-15, conflict-free), ONE barrier, then each
// thread combines 8 partials with weights mw_k/W (W = max_k mw_k == round-9's
// W; S += lnW + C identical). Removes: global-W-before-quantize, Pq write,
// barrier 1, 8x b128 Pq reads. Precision equal-or-better (tighter quant max).

constexpr int Bn = 64, Tn = 1024, Sn = 512;
#define L2E 1.44269504f

typedef int v4i __attribute__((ext_vector_type(4)));

#if __has_builtin(__builtin_amdgcn_update_dpp)
template <int CTRL>
__device__ __forceinline__ float dpp_fmax(float x) {
    int s = __builtin_bit_cast(int, x);
    int d = __builtin_amdgcn_update_dpp(s, s, CTRL, 0xf, 0xf, false);
    return fmaxf(x, __builtin_bit_cast(float, d));
}
__device__ __forceinline__ float wave_max64(float x) {
    x = dpp_fmax<0x121>(x);   // row_ror:1
    x = dpp_fmax<0x122>(x);   // row_ror:2
    x = dpp_fmax<0x124>(x);   // row_ror:4
    x = dpp_fmax<0x128>(x);   // row_ror:8
    x = dpp_fmax<0x142>(x);   // row_bcast:15
    x = dpp_fmax<0x143>(x);   // row_bcast:31
    return __builtin_bit_cast(float,
        __builtin_amdgcn_readlane(__builtin_bit_cast(int, x), 63));
}
template <int CTRL>
__device__ __forceinline__ int dpp_mov_i(int x) {
    return __builtin_amdgcn_update_dpp(x, x, CTRL, 0xf, 0xf, false);
}
#else
__device__ __forceinline__ float wave_max64(float x) {
    #pragma unroll
    for (int off = 32; off; off >>= 1) x = fmaxf(x, __shfl_xor(x, off, 64));
    return x;
}
#endif

// Eq value for (row i, col c) -> B-fragment byte address:
// frag = (c>>4)*8 + (i>>6); lane = ((i>>4)&3)*16 + (c&15); byte = i&15
__device__ __forceinline__ int bfrag_addr(int i, int c) {
    return ((((c >> 4) * 8 + (i >> 6)) * 64) + ((i >> 4) & 3) * 16 + (c & 15)) * 16
           + (i & 15);
}

// One block per row i: rowmax + quantize row to u8, scatter into B-frag layout.
__global__ __launch_bounds__(256) void prep_rows(
    const float* __restrict__ trans, unsigned char* __restrict__ EqB,
    float* __restrict__ rowmax)
{
    const int i = blockIdx.x;
    const int j = threadIdx.x;
    const int lane = j & 63, wv = j >> 6;
    float t0 = trans[i * Sn + j];
    float t1 = trans[i * Sn + j + 256];
    float m = fmaxf(t0, t1);
    #pragma unroll
    for (int off = 32; off; off >>= 1) m = fmaxf(m, __shfl_xor(m, off, 64));
    __shared__ float rm[4];
    if (lane == 0) rm[wv] = m;
    __syncthreads();
    m = fmaxf(fmaxf(rm[0], rm[1]), fmaxf(rm[2], rm[3]));
    if (j == 0) rowmax[i] = m;
    int q0 = __float2int_rn(127.f * __expf(t0 - m));
    int q1 = __float2int_rn(127.f * __expf(t1 - m));
    EqB[bfrag_addr(i, j)] = (unsigned char)q0;
    EqB[bfrag_addr(i, j + 256)] = (unsigned char)q1;
}

__global__ __launch_bounds__(512, 2) void hmm_fwd(
    const int* __restrict__ obs,          // [B, T]
    const float* __restrict__ emis,       // [V, S]
    const float* __restrict__ prior,      // [S]
    const v4i* __restrict__ EqB4,         // B-fragments, 16B per (frag,lane)
    const float* __restrict__ rowmax,     // [S]
    float* __restrict__ out)              // [B]
{
    const int b = blockIdx.x;
    const int tid = threadIdx.x;          // state j owned by this thread
    const int lane = tid & 63, wv = tid >> 6;

    __shared__ int obs_s[Tn + 1];
    __shared__ int part[2][8][Sn];        // partial dots, [parity][kap][col]
    __shared__ __align__(16) float redm[2][8];
    __shared__ float reds[8];

    int o0 = obs[b * Tn + tid];
    int o1 = obs[b * Tn + 512 + tid];
    obs_s[tid] = o0;
    obs_s[tid + 512] = o1;
    if (tid == 511) obs_s[Tn] = o1;       // pad: branch-free prefetch

    // B-fragments: wave wv's OWN k-chunk (E rows wv*64..+63) x ALL 512 cols:
    // Bg[tau] covers cols tau*16..+15; frag = tau*8 + wv in the EqB layout.
    v4i Bg[32];
    #pragma unroll
    for (int tau = 0; tau < 32; ++tau)
        Bg[tau] = EqB4[(tau * 8 + wv) * 64 + lane];

    // ---- fused prep_scale: RM = max_i rowmax[i]; lrf_j = 127*exp(rowmax_j-RM)
    float rmj = rowmax[tid];
    {
        float r = wave_max64(rmj);
        if (lane == 0) redm[0][wv] = r;
    }
    __syncthreads();   // covers obs_s staging AND redm[0]
    float RM;
    {
        float4 r0 = *(const float4*)&redm[0][0];
        float4 r1 = *(const float4*)&redm[0][4];
        RM = fmaxf(fmaxf(fmaxf(r0.x, r0.y), fmaxf(r0.z, r0.w)),
                   fmaxf(fmaxf(r1.x, r1.y), fmaxf(r1.z, r1.w)));
    }
    const float lrf = exp2f((rmj - RM) * L2E + 6.98868469f);  // log2(127)
    const float C = RM - 9.68837417f;                          // 2*ln(127)

    // alpha_0 in exp form: a_j = S + ln(wd_j), S = 0
    float wd = __expf(emis[obs_s[0] * Sn + tid] + prior[tid]);
    float lw = lrf * wd;
    float S = 0.f;
    float eC = emis[obs_s[1] * Sn + tid];   // raw emission for step 1

    const v4i zz = {0, 0, 0, 0};

    for (int t = 1; t < Tn; ++t) {
        const int pb = t & 1;

        // ---- Phase A (in-wave, no barrier): wave-local max + quantize + pack
        float mw = wave_max64(wd);
        if (lane == 0) redm[pb][wv] = mw;
        int gi = __float2int_rn(lw * __builtin_amdgcn_rcpf(mw));  // 0..127

#if __has_builtin(__builtin_amdgcn_update_dpp)
        // pair pack: P2 = bytes of lanes (2m, 2m+1), identical across the pair
        int sw1 = dpp_mov_i<0xB1>(gi);            // quad_perm [1,0,3,2]
        int sh1 = (lane & 1) << 3;
        int P2 = (gi << sh1) | (sw1 << (8 - sh1));
        // quad pack: D = bytes of lanes (4m..4m+3), identical across the quad
        int sw2 = dpp_mov_i<0x4E>(P2);            // quad_perm [2,3,0,1]
        int sh2 = (lane & 2) << 3;
        int D = (P2 << sh2) | (sw2 << (16 - sh2));
        // gather the 16-group's 4 quad dwords: lane' = (lane&0x10)|4k per half
        v4i Af;
        Af.x = __builtin_amdgcn_ds_swizzle(D, 0x0010);
        Af.y = __builtin_amdgcn_ds_swizzle(D, 0x0090);
        Af.z = __builtin_amdgcn_ds_swizzle(D, 0x0110);
        Af.w = __builtin_amdgcn_ds_swizzle(D, 0x0190);
#else
        v4i Af = zz;  // (non-DPP fallback not exercised on gfx950)
#endif

        // ---- Phase B: 32 independent MFMAs, 4 batches of 8 + masked writes
        #pragma unroll
        for (int bt = 0; bt < 4; ++bt) {
            v4i acc[8];
            #pragma unroll
            for (int s2 = 0; s2 < 8; ++s2)
                acc[s2] = __builtin_amdgcn_mfma_i32_16x16x64_i8(
                              Af, Bg[bt * 8 + s2], zz, 0, 0, 0);
            if (lane < 16) {
                #pragma unroll
                for (int s2 = 0; s2 < 8; ++s2)
                    part[pb][wv][(bt * 8 + s2) * 16 + lane] = acc[s2].x;
            }
        }

        int oN = obs_s[t + 1];                    // LDS read, off-path
        __syncthreads();                          // the ONLY barrier per step

        // ---- Phase D: combine 8 weighted partials
        float4 r0 = *(const float4*)&redm[pb][0];
        float4 r1 = *(const float4*)&redm[pb][4];
        float W = fmaxf(fmaxf(fmaxf(r0.x, r0.y), fmaxf(r0.z, r0.w)),
                        fmaxf(fmaxf(r1.x, r1.y), fmaxf(r1.z, r1.w)));
        float rcpW = __builtin_amdgcn_rcpf(W);

        int p0 = part[pb][0][tid], p1 = part[pb][1][tid];
        int p2 = part[pb][2][tid], p3 = part[pb][3][tid];
        int p4 = part[pb][4][tid], p5 = part[pb][5][tid];
        int p6 = part[pb][6][tid], p7 = part[pb][7][tid];

        float w0 = r0.x * rcpW, w1 = r0.y * rcpW;
        float w2 = r0.z * rcpW, w3 = r0.w * rcpW;
        float w4 = r1.x * rcpW, w5 = r1.y * rcpW;
        float w6 = r1.z * rcpW, w7 = r1.w * rcpW;

        float F = ((w0 * (float)p0 + w1 * (float)p1)
                 + (w2 * (float)p2 + w3 * (float)p3))
                + ((w4 * (float)p4 + w5 * (float)p5)
                 + (w6 * (float)p6 + w7 * (float)p7));

        float weC = __expf(eC);                   // TRANS, short dep
        wd = weC * F;
        lw = lrf * wd;

        S += __logf(W) + C;                       // off-path scalar accumulate
        eC = emis[oN * Sn + tid];                 // prefetch t+1 (hidden)
    }

    // ---- out[b] = S + ln(sum_j wd_j)  via max-normalized sum
    float mwf = wave_max64(wd);
    if (lane == 0) redm[0][wv] = mwf;
    __syncthreads();
    float Wf = mwf;
    #pragma unroll
    for (int w = 0; w < 8; ++w) Wf = fmaxf(Wf, redm[0][w]);

    float s = wd * __builtin_amdgcn_rcpf(Wf);
    #pragma unroll
    for (int off = 32; off; off >>= 1) s += __shfl_xor(s, off, 64);
    if (lane == 0) reds[wv] = s;
    __syncthreads();
    if (tid == 0) {
        float tot = 0.f;
        #pragma unroll
        for (int w = 0; w < 8; ++w) tot += reds[w];
        out[b] = S + __logf(Wf) + __logf(tot);
    }
}

extern "C" void kernel_launch(void* const* d_in, const int* in_sizes, int n_in,
                              void* d_out, int out_size, void* d_ws, size_t ws_size,
                              hipStream_t stream) {
    const int*   obs   = (const int*)d_in[0];
    const float* emis  = (const float*)d_in[1];
    const float* trans = (const float*)d_in[2];
    const float* prior = (const float*)d_in[3];
    float* out = (float*)d_out;

    unsigned char* EqB = (unsigned char*)d_ws;                // 256 KB
    float* rowmax = (float*)(EqB + Sn * Sn);                  // 2 KB

    prep_rows<<<Sn, 256, 0, stream>>>(trans, EqB, rowmax);
    hmm_fwd<<<Bn, Sn, 0, stream>>>(obs, emis, prior,
                                   (const v4i*)EqB, rowmax, out);
}

// Round 12
// 1061.587 us; speedup vs baseline: 1.1486x; 1.1486x over previous
//
#include <hip/hip_runtime.h>

// HMM forward, B=64, T=1024, S=512, V=1024.
// Round 12: round-9 structure (854 us dispatch, champion) + PRE-BARRIER MFMA
// HEAD START. After quantize, each wave packs its OWN 64 bytes into an
// A-fragment in-register (2 DPP quad-perms + shifts + 4 ds_swizzle quad
// gathers -- hardware-verified in round 11) and issues the 4 chain-starting
// MFMAs (own kap, zero C) BEFORE barrier 2. Post-barrier, chains continue
// over the other 7 kaps (static loop, wave-uniform kap!=wv skip). Hides the
// barrier wait + first Af ds_read_b128 latency under real MFMA issue.
// Integer sum bit-identical (i32 adds commute). S-accumulate moved after
// MFMA issue. Everything else identical to round 9 (exp-domain ring, exact
// global max, 2 barriers, fused prep_scale).

constexpr int Bn = 64, Tn = 1024, Sn = 512;
#define L2E 1.44269504f

typedef int v4i __attribute__((ext_vector_type(4)));

#if __has_builtin(__builtin_amdgcn_update_dpp)
template <int CTRL>
__device__ __forceinline__ float dpp_fmax(float x) {
    int s = __builtin_bit_cast(int, x);
    int d = __builtin_amdgcn_update_dpp(s, s, CTRL, 0xf, 0xf, false);
    return fmaxf(x, __builtin_bit_cast(float, d));
}
// Full-wave max; result valid in lane 63 (no readlane broadcast).
__device__ __forceinline__ float wave_max64_l63(float x) {
    x = dpp_fmax<0x121>(x);   // row_ror:1
    x = dpp_fmax<0x122>(x);   // row_ror:2
    x = dpp_fmax<0x124>(x);   // row_ror:4
    x = dpp_fmax<0x128>(x);   // row_ror:8
    x = dpp_fmax<0x142>(x);   // row_bcast:15
    x = dpp_fmax<0x143>(x);   // row_bcast:31
    return x;
}
__device__ __forceinline__ float wave_max64(float x) {
    return __builtin_bit_cast(float,
        __builtin_amdgcn_readlane(
            __builtin_bit_cast(int, wave_max64_l63(x)), 63));
}
template <int CTRL>
__device__ __forceinline__ int dpp_mov_i(int x) {
    return __builtin_amdgcn_update_dpp(x, x, CTRL, 0xf, 0xf, false);
}
#else
__device__ __forceinline__ float wave_max64(float x) {
    #pragma unroll
    for (int off = 32; off; off >>= 1) x = fmaxf(x, __shfl_xor(x, off, 64));
    return x;
}
__device__ __forceinline__ float wave_max64_l63(float x) { return wave_max64(x); }
#endif

// Eq value for (row i, col c) -> B-fragment byte address:
// frag = (c>>4)*8 + (i>>6); lane = ((i>>4)&3)*16 + (c&15); byte = i&15
__device__ __forceinline__ int bfrag_addr(int i, int c) {
    return ((((c >> 4) * 8 + (i >> 6)) * 64) + ((i >> 4) & 3) * 16 + (c & 15)) * 16
           + (i & 15);
}

// One block per row i: rowmax + quantize row to u8, scatter into B-frag layout.
__global__ __launch_bounds__(256) void prep_rows(
    const float* __restrict__ trans, unsigned char* __restrict__ EqB,
    float* __restrict__ rowmax)
{
    const int i = blockIdx.x;
    const int j = threadIdx.x;
    const int lane = j & 63, wv = j >> 6;
    float t0 = trans[i * Sn + j];
    float t1 = trans[i * Sn + j + 256];
    float m = fmaxf(t0, t1);
    #pragma unroll
    for (int off = 32; off; off >>= 1) m = fmaxf(m, __shfl_xor(m, off, 64));
    __shared__ float rm[4];
    if (lane == 0) rm[wv] = m;
    __syncthreads();
    m = fmaxf(fmaxf(rm[0], rm[1]), fmaxf(rm[2], rm[3]));
    if (j == 0) rowmax[i] = m;
    int q0 = __float2int_rn(127.f * __expf(t0 - m));
    int q1 = __float2int_rn(127.f * __expf(t1 - m));
    EqB[bfrag_addr(i, j)] = (unsigned char)q0;
    EqB[bfrag_addr(i, j + 256)] = (unsigned char)q1;
}

__global__ __launch_bounds__(512, 2) void hmm_fwd(
    const int* __restrict__ obs,          // [B, T]
    const float* __restrict__ emis,       // [V, S]
    const float* __restrict__ prior,      // [S]
    const v4i* __restrict__ EqB4,         // B-fragments, 16B per (frag,lane)
    const float* __restrict__ rowmax,     // [S]
    float* __restrict__ out)              // [B]
{
    const int b = blockIdx.x;
    const int tid = threadIdx.x;          // state j owned by this thread
    const int lane = tid & 63, wv = tid >> 6;
    const int q = lane >> 4;

    __shared__ int obs_s[Tn + 1];
    __shared__ __align__(16) unsigned char Pq[Sn];
    __shared__ __align__(16) float redm[8];
    __shared__ float reds[8];

    int o0 = obs[b * Tn + tid];
    int o1 = obs[b * Tn + 512 + tid];
    obs_s[tid] = o0;
    obs_s[tid + 512] = o1;
    if (tid == 511) obs_s[Tn] = o1;       // pad: branch-free prefetch

    // B-fragments: Bf[tau][kap] = E rows kap*64+(16k-subchunks), cols wv*64+tau*16+(lane&15)
    v4i Bf[4][8];
    #pragma unroll
    for (int tau = 0; tau < 4; ++tau)
        #pragma unroll
        for (int kap = 0; kap < 8; ++kap)
            Bf[tau][kap] = EqB4[((wv * 4 + tau) * 8 + kap) * 64 + lane];

    // Own-chunk B-fragments (kap == wv), separate regs for static indexing.
    v4i BfO[4];
    #pragma unroll
    for (int tau = 0; tau < 4; ++tau)
        BfO[tau] = EqB4[((wv * 4 + tau) * 8 + wv) * 64 + lane];

    // ---- fused prep_scale: RM = max_i rowmax[i]; lrf_j = 127*exp(rowmax_j-RM)
    float rmj = rowmax[tid];
    {
        float r = wave_max64(rmj);
        if (lane == 0) redm[wv] = r;
    }
    __syncthreads();   // covers obs_s staging AND redm
    float RM;
    {
        float4 r0 = *(const float4*)&redm[0];
        float4 r1 = *(const float4*)&redm[4];
        RM = fmaxf(fmaxf(fmaxf(r0.x, r0.y), fmaxf(r0.z, r0.w)),
                   fmaxf(fmaxf(r1.x, r1.y), fmaxf(r1.z, r1.w)));
    }
    const float lrf = exp2f((rmj - RM) * L2E + 6.98868469f);  // log2(127)
    const float C = RM - 9.68837417f;                          // 2*ln(127)

    // alpha_0 in exp form: a_j = S + ln(wd_j), S = 0
    float wd = __expf(emis[obs_s[0] * Sn + tid] + prior[tid]);
    float lw = lrf * wd;
    float S = 0.f;
    float eC = emis[obs_s[1] * Sn + tid];   // raw emission for step 1

    const v4i zz = {0, 0, 0, 0};

    for (int t = 1; t < Tn; ++t) {
        // ---- exact block max of wd: DPP in-wave (result in lane 63)
        float mx = wave_max64_l63(wd);
        if (lane == 63) redm[wv] = mx;
        int oN = obs_s[t + 1];                    // early LDS read (hidden)
        __syncthreads();                          // barrier 1
        float4 r0 = *(const float4*)&redm[0];
        float4 r1 = *(const float4*)&redm[4];
        float W = fmaxf(fmaxf(fmaxf(r0.x, r0.y), fmaxf(r0.z, r0.w)),
                        fmaxf(fmaxf(r1.x, r1.y), fmaxf(r1.z, r1.w)));

        float weC = __expf(eC);                   // TRANS, off-path

        // ---- quantize: q = round(lrf * wd / W)
        float rw = __builtin_amdgcn_rcpf(W);
        int gi = __float2int_rn(lw * rw);
        Pq[tid] = (unsigned char)gi;

#if __has_builtin(__builtin_amdgcn_update_dpp)
        // ---- DPP pack of OWN chunk (r11-verified): AfO == Af[wv] byte-exact
        int sw1 = dpp_mov_i<0xB1>(gi);            // quad_perm [1,0,3,2]
        int sh1 = (lane & 1) << 3;
        int P2 = (gi << sh1) | (sw1 << (8 - sh1));
        int sw2 = dpp_mov_i<0x4E>(P2);            // quad_perm [2,3,0,1]
        int sh2 = (lane & 2) << 3;
        int D = (P2 << sh2) | (sw2 << (16 - sh2));
        v4i AfO;
        AfO.x = __builtin_amdgcn_ds_swizzle(D, 0x0010);
        AfO.y = __builtin_amdgcn_ds_swizzle(D, 0x0090);
        AfO.z = __builtin_amdgcn_ds_swizzle(D, 0x0110);
        AfO.w = __builtin_amdgcn_ds_swizzle(D, 0x0190);

        // ---- pre-barrier chain starts: 4 MFMAs on own chunk (zero C)
        v4i a0 = __builtin_amdgcn_mfma_i32_16x16x64_i8(AfO, BfO[0], zz, 0, 0, 0);
        v4i a1 = __builtin_amdgcn_mfma_i32_16x16x64_i8(AfO, BfO[1], zz, 0, 0, 0);
        v4i a2 = __builtin_amdgcn_mfma_i32_16x16x64_i8(AfO, BfO[2], zz, 0, 0, 0);
        v4i a3 = __builtin_amdgcn_mfma_i32_16x16x64_i8(AfO, BfO[3], zz, 0, 0, 0);
        __syncthreads();                          // barrier 2

        eC = emis[oN * Sn + tid];                 // prefetch t+1 (hidden by MFMA)

        // ---- remaining 7 chunks from LDS (static indexing, skip own)
        const unsigned char* Pbase = Pq + q * 16;
        v4i Af[8];
        #pragma unroll
        for (int kap = 0; kap < 8; ++kap)
            Af[kap] = *(const v4i*)(Pbase + kap * 64);
        #pragma unroll
        for (int kap = 0; kap < 8; ++kap) {
            if (kap != wv) {                      // wave-uniform branch
                a0 = __builtin_amdgcn_mfma_i32_16x16x64_i8(Af[kap], Bf[0][kap], a0, 0, 0, 0);
                a1 = __builtin_amdgcn_mfma_i32_16x16x64_i8(Af[kap], Bf[1][kap], a1, 0, 0, 0);
                a2 = __builtin_amdgcn_mfma_i32_16x16x64_i8(Af[kap], Bf[2][kap], a2, 0, 0, 0);
                a3 = __builtin_amdgcn_mfma_i32_16x16x64_i8(Af[kap], Bf[3][kap], a3, 0, 0, 0);
            }
        }
#else
        __syncthreads();                          // barrier 2 (fallback path)
        eC = emis[oN * Sn + tid];
        const unsigned char* Pbase = Pq + q * 16;
        v4i Af[8];
        #pragma unroll
        for (int kap = 0; kap < 8; ++kap)
            Af[kap] = *(const v4i*)(Pbase + kap * 64);
        v4i a0 = zz, a1 = zz, a2 = zz, a3 = zz;
        #pragma unroll
        for (int kap = 0; kap < 8; ++kap) {
            a0 = __builtin_amdgcn_mfma_i32_16x16x64_i8(Af[kap], Bf[0][kap], a0, 0, 0, 0);
            a1 = __builtin_amdgcn_mfma_i32_16x16x64_i8(Af[kap], Bf[1][kap], a1, 0, 0, 0);
            a2 = __builtin_amdgcn_mfma_i32_16x16x64_i8(Af[kap], Bf[2][kap], a2, 0, 0, 0);
            a3 = __builtin_amdgcn_mfma_i32_16x16x64_i8(Af[kap], Bf[3][kap], a3, 0, 0, 0);
        }
#endif

        S += __logf(W) + C;                       // off-path, after MFMA issue

        // ---- every C row equals the result: select tau = lane>>4 in-register
        int idot = (lane < 16) ? a0.x
                 : (lane < 32) ? a1.x
                 : (lane < 48) ? a2.x
                               : a3.x;

        // ---- alpha update in exp form
        wd = weC * (float)idot;
        lw = lrf * wd;
    }

    // ---- out[b] = S + ln(sum_j wd_j)  via max-normalized sum
    float mw = wave_max64(wd);
    if (lane == 0) redm[wv] = mw;
    __syncthreads();
    float Wf = mw;
    #pragma unroll
    for (int w = 0; w < 8; ++w) Wf = fmaxf(Wf, redm[w]);

    float s = wd * __builtin_amdgcn_rcpf(Wf);
    #pragma unroll
    for (int off = 32; off; off >>= 1) s += __shfl_xor(s, off, 64);
    if (lane == 0) reds[wv] = s;
    __syncthreads();
    if (tid == 0) {
        float tot = 0.f;
        #pragma unroll
        for (int w = 0; w < 8; ++w) tot += reds[w];
        out[b] = S + __logf(Wf) + __logf(tot);
    }
}

extern "C" void kernel_launch(void* const* d_in, const int* in_sizes, int n_in,
                              void* d_out, int out_size, void* d_ws, size_t ws_size,
                              hipStream_t stream) {
    const int*   obs   = (const int*)d_in[0];
    const float* emis  = (const float*)d_in[1];
    const float* trans = (const float*)d_in[2];
    const float* prior = (const float*)d_in[3];
    float* out = (float*)d_out;

    unsigned char* EqB = (unsigned char*)d_ws;                // 256 KB
    float* rowmax = (float*)(EqB + Sn * Sn);                  // 2 KB

    prep_rows<<<Sn, 256, 0, stream>>>(trans, EqB, rowmax);
    hmm_fwd<<<Bn, Sn, 0, stream>>>(obs, emis, prior,
                                   (const v4i*)EqB, rowmax, out);
}

// Round 13
// 901.043 us; speedup vs baseline: 1.3532x; 1.1782x over previous
//
#include <hip/hip_runtime.h>

// HMM forward, B=64, T=1024, S=512, V=1024.
// Round 13: byte-exact restore of the round-9 champion (854 us dispatch).
// Structure: one block per batch; E = exp(trans) u8 B-fragments in 128 AGPRs;
// exp-domain ring (no log/exp on the critical path); exact global max via
// DPP + one LDS round-trip; 2 barriers/step; 256 x mfma_i32_16x16x64_i8
// chained-accumulator (4 tau-chains x 8 kap); fused prep_scale.
// Step = 2004 cyc = MFMA wall 1022 (invariant: 256 MFMA / 4 SIMD x 16 cyc)
// + serial ring ~980. All structural alternatives measured dead (rounds
// 1-4, 8, 10-12); within-structure shaves exhausted (rounds 6, 7, 9).

constexpr int Bn = 64, Tn = 1024, Sn = 512;
#define L2E 1.44269504f

typedef int v4i __attribute__((ext_vector_type(4)));

#if __has_builtin(__builtin_amdgcn_update_dpp)
template <int CTRL>
__device__ __forceinline__ float dpp_fmax(float x) {
    int s = __builtin_bit_cast(int, x);
    int d = __builtin_amdgcn_update_dpp(s, s, CTRL, 0xf, 0xf, false);
    return fmaxf(x, __builtin_bit_cast(float, d));
}
// Full-wave max; result valid in lane 63 (no readlane broadcast).
__device__ __forceinline__ float wave_max64_l63(float x) {
    x = dpp_fmax<0x121>(x);   // row_ror:1
    x = dpp_fmax<0x122>(x);   // row_ror:2
    x = dpp_fmax<0x124>(x);   // row_ror:4
    x = dpp_fmax<0x128>(x);   // row_ror:8
    x = dpp_fmax<0x142>(x);   // row_bcast:15
    x = dpp_fmax<0x143>(x);   // row_bcast:31
    return x;
}
__device__ __forceinline__ float wave_max64(float x) {
    return __builtin_bit_cast(float,
        __builtin_amdgcn_readlane(
            __builtin_bit_cast(int, wave_max64_l63(x)), 63));
}
#else
__device__ __forceinline__ float wave_max64(float x) {
    #pragma unroll
    for (int off = 32; off; off >>= 1) x = fmaxf(x, __shfl_xor(x, off, 64));
    return x;
}
__device__ __forceinline__ float wave_max64_l63(float x) { return wave_max64(x); }
#endif

// Eq value for (row i, col c) -> B-fragment byte address:
// frag = (c>>4)*8 + (i>>6); lane = ((i>>4)&3)*16 + (c&15); byte = i&15
__device__ __forceinline__ int bfrag_addr(int i, int c) {
    return ((((c >> 4) * 8 + (i >> 6)) * 64) + ((i >> 4) & 3) * 16 + (c & 15)) * 16
           + (i & 15);
}

// One block per row i: rowmax + quantize row to u8, scatter into B-frag layout.
__global__ __launch_bounds__(256) void prep_rows(
    const float* __restrict__ trans, unsigned char* __restrict__ EqB,
    float* __restrict__ rowmax)
{
    const int i = blockIdx.x;
    const int j = threadIdx.x;
    const int lane = j & 63, wv = j >> 6;
    float t0 = trans[i * Sn + j];
    float t1 = trans[i * Sn + j + 256];
    float m = fmaxf(t0, t1);
    #pragma unroll
    for (int off = 32; off; off >>= 1) m = fmaxf(m, __shfl_xor(m, off, 64));
    __shared__ float rm[4];
    if (lane == 0) rm[wv] = m;
    __syncthreads();
    m = fmaxf(fmaxf(rm[0], rm[1]), fmaxf(rm[2], rm[3]));
    if (j == 0) rowmax[i] = m;
    int q0 = __float2int_rn(127.f * __expf(t0 - m));
    int q1 = __float2int_rn(127.f * __expf(t1 - m));
    EqB[bfrag_addr(i, j)] = (unsigned char)q0;
    EqB[bfrag_addr(i, j + 256)] = (unsigned char)q1;
}

__global__ __launch_bounds__(512, 2) void hmm_fwd(
    const int* __restrict__ obs,          // [B, T]
    const float* __restrict__ emis,       // [V, S]
    const float* __restrict__ prior,      // [S]
    const v4i* __restrict__ EqB4,         // B-fragments, 16B per (frag,lane)
    const float* __restrict__ rowmax,     // [S]
    float* __restrict__ out)              // [B]
{
    const int b = blockIdx.x;
    const int tid = threadIdx.x;          // state j owned by this thread
    const int lane = tid & 63, wv = tid >> 6;
    const int q = lane >> 4;

    __shared__ int obs_s[Tn + 1];
    __shared__ __align__(16) unsigned char Pq[Sn];
    __shared__ __align__(16) float redm[8];
    __shared__ float reds[8];

    int o0 = obs[b * Tn + tid];
    int o1 = obs[b * Tn + 512 + tid];
    obs_s[tid] = o0;
    obs_s[tid + 512] = o1;
    if (tid == 511) obs_s[Tn] = o1;       // pad: branch-free prefetch

    // B-fragments: Bf[tau][kap] = E rows kap*64+(16k-subchunks), cols wv*64+tau*16+(lane&15)
    v4i Bf[4][8];
    #pragma unroll
    for (int tau = 0; tau < 4; ++tau)
        #pragma unroll
        for (int kap = 0; kap < 8; ++kap)
            Bf[tau][kap] = EqB4[((wv * 4 + tau) * 8 + kap) * 64 + lane];

    // ---- fused prep_scale: RM = max_i rowmax[i]; lrf_j = 127*exp(rowmax_j-RM)
    float rmj = rowmax[tid];
    {
        float r = wave_max64(rmj);
        if (lane == 0) redm[wv] = r;
    }
    __syncthreads();   // covers obs_s staging AND redm
    float RM;
    {
        float4 r0 = *(const float4*)&redm[0];
        float4 r1 = *(const float4*)&redm[4];
        RM = fmaxf(fmaxf(fmaxf(r0.x, r0.y), fmaxf(r0.z, r0.w)),
                   fmaxf(fmaxf(r1.x, r1.y), fmaxf(r1.z, r1.w)));
    }
    const float lrf = exp2f((rmj - RM) * L2E + 6.98868469f);  // log2(127)
    const float C = RM - 9.68837417f;                          // 2*ln(127)

    // alpha_0 in exp form: a_j = S + ln(wd_j), S = 0
    float wd = __expf(emis[obs_s[0] * Sn + tid] + prior[tid]);
    float lw = lrf * wd;
    float S = 0.f;
    float eC = emis[obs_s[1] * Sn + tid];   // raw emission for step 1

    for (int t = 1; t < Tn; ++t) {
        // ---- exact block max of wd: DPP in-wave (result in lane 63)
        float mx = wave_max64_l63(wd);
        if (lane == 63) redm[wv] = mx;
        int oN = obs_s[t + 1];                    // early LDS read (hidden)
        __syncthreads();                          // barrier 1
        float4 r0 = *(const float4*)&redm[0];
        float4 r1 = *(const float4*)&redm[4];
        float W = fmaxf(fmaxf(fmaxf(r0.x, r0.y), fmaxf(r0.z, r0.w)),
                        fmaxf(fmaxf(r1.x, r1.y), fmaxf(r1.z, r1.w)));

        float weC = __expf(eC);                   // TRANS, off-path

        // ---- quantize: q = round(lrf * wd / W)
        float rw = __builtin_amdgcn_rcpf(W);
        int gi = __float2int_rn(lw * rw);
        Pq[tid] = (unsigned char)gi;
        __syncthreads();                          // barrier 2

        eC = emis[oN * Sn + tid];                 // prefetch t+1 (hidden by MFMA)
        S += __logf(W) + C;                       // off-path scalar accumulate

        // ---- A-fragments: quad-broadcast reads of P (all 16 A-rows identical)
        const unsigned char* Pbase = Pq + q * 16;
        v4i Af[8];
        #pragma unroll
        for (int kap = 0; kap < 8; ++kap)
            Af[kap] = *(const v4i*)(Pbase + kap * 64);

        // ---- 4 n-tiles x 8 k-chunks of mfma_i32_16x16x64_i8
        v4i acc[4];
        #pragma unroll
        for (int tau = 0; tau < 4; ++tau) {
            v4i z = {0, 0, 0, 0};
            #pragma unroll
            for (int kap = 0; kap < 8; ++kap)
                z = __builtin_amdgcn_mfma_i32_16x16x64_i8(Af[kap], Bf[tau][kap],
                                                          z, 0, 0, 0);
            acc[tau] = z;
        }

        // ---- every C row equals the result: select tau = lane>>4 in-register
        int idot = (lane < 16) ? acc[0].x
                 : (lane < 32) ? acc[1].x
                 : (lane < 48) ? acc[2].x
                               : acc[3].x;

        // ---- alpha update in exp form
        wd = weC * (float)idot;
        lw = lrf * wd;
    }

    // ---- out[b] = S + ln(sum_j wd_j)  via max-normalized sum
    float mw = wave_max64(wd);
    if (lane == 0) redm[wv] = mw;
    __syncthreads();
    float Wf = mw;
    #pragma unroll
    for (int w = 0; w < 8; ++w) Wf = fmaxf(Wf, redm[w]);

    float s = wd * __builtin_amdgcn_rcpf(Wf);
    #pragma unroll
    for (int off = 32; off; off >>= 1) s += __shfl_xor(s, off, 64);
    if (lane == 0) reds[wv] = s;
    __syncthreads();
    if (tid == 0) {
        float tot = 0.f;
        #pragma unroll
        for (int w = 0; w < 8; ++w) tot += reds[w];
        out[b] = S + __logf(Wf) + __logf(tot);
    }
}

extern "C" void kernel_launch(void* const* d_in, const int* in_sizes, int n_in,
                              void* d_out, int out_size, void* d_ws, size_t ws_size,
                              hipStream_t stream) {
    const int*   obs   = (const int*)d_in[0];
    const float* emis  = (const float*)d_in[1];
    const float* trans = (const float*)d_in[2];
    const float* prior = (const float*)d_in[3];
    float* out = (float*)d_out;

    unsigned char* EqB = (unsigned char*)d_ws;                // 256 KB
    float* rowmax = (float*)(EqB + Sn * Sn);                  // 2 KB

    prep_rows<<<Sn, 256, 0, stream>>>(trans, EqB, rowmax);
    hmm_fwd<<<Bn, Sn, 0, stream>>>(obs, emis, prior,
                                   (const v4i*)EqB, rowmax, out);
}